// Round 9
// baseline (80.116 us; speedup 1.0000x reference)
//
#include <hip/hip_runtime.h>
#include <hip/hip_bf16.h>

#define LEN   2048
#define KNB   32
#define HID   128
#define FS    432   // fp8 bytes/feature-row; mult of 16; 108 dw % 32 = 12

typedef unsigned long long ull;
typedef unsigned int uint32;
typedef float f32x4 __attribute__((ext_vector_type(4)));

// ---------------------------------------------------------------------------
// Kernel 0: prep — pack CA+mask as float4; convert W_edge f32 -> fp8 e4m3.
// ---------------------------------------------------------------------------
__global__ __launch_bounds__(256) void prep_kernel(
    const float* __restrict__ X, const float* __restrict__ mask,
    const float* __restrict__ W_edge,
    float4* __restrict__ CAm, int* __restrict__ Wf8) {
    const int t = blockIdx.x * 256 + threadIdx.x;
    if (t < 2 * LEN) {
        const float* p = X + (size_t)t * 12;
        CAm[t] = make_float4(p[3], p[4], p[5],
                             __fmul_rn(__fsub_rn(1.0f, mask[t]), 1000000.0f));
    }
    if (t < 13312) {
        const float4 w = ((const float4*)W_edge)[t];
        int r = __builtin_amdgcn_cvt_pk_fp8_f32(w.x, w.y, 0, false);
        r = __builtin_amdgcn_cvt_pk_fp8_f32(w.z, w.w, r, true);
        Wf8[t] = r;
    }
}

// ---------------------------------------------------------------------------
// Fused kernel: per block (512 thr, 8 waves) — topk(4 rows) -> gather ->
// {features -> fp8 GEMM -> LN} x 4. topk's cand/hist LDS is union-aliased
// onto featF8/hbuf (dead during prologue). RBF via geometric recurrence
// (2 exp + 30 mul instead of 16 exp). W register-resident fp8 (26 regs).
// ---------------------------------------------------------------------------
__device__ __forceinline__ void load_res_atoms(const float* __restrict__ p, float* dst) {
    const float Nx = p[0], Ny = p[1], Nz = p[2];
    const float Ax = p[3], Ay = p[4], Az = p[5];
    const float Cx = p[6], Cy = p[7], Cz = p[8];
    const float Ox = p[9], Oy = p[10], Oz = p[11];
    const float bx = Ax - Nx, by = Ay - Ny, bz = Az - Nz;
    const float cx = Cx - Ax, cy = Cy - Ay, cz = Cz - Az;
    const float axv = by * cz - bz * cy;
    const float ayv = bz * cx - bx * cz;
    const float azv = bx * cy - by * cx;
    dst[0] = Nx;  dst[1] = Ny;  dst[2] = Nz;
    dst[3] = Ax;  dst[4] = Ay;  dst[5] = Az;
    dst[6] = Cx;  dst[7] = Cy;  dst[8] = Cz;
    dst[9] = Ox;  dst[10] = Oy; dst[11] = Oz;
    dst[12] = -0.58273431f * axv + 0.56802827f * bx + -0.54067466f * cx + Ax;
    dst[13] = -0.58273431f * ayv + 0.56802827f * by + -0.54067466f * cy +Ay;
    dst[14] = -0.58273431f * azv + 0.56802827f * bz + -0.54067466f * cz + Az;
}

__device__ __forceinline__ int pk4(float a, float b, float c, float d) {
    int r = __builtin_amdgcn_cvt_pk_fp8_f32(a, b, 0, false);
    return __builtin_amdgcn_cvt_pk_fp8_f32(c, d, r, true);
}

// step constants exp(-1.13777778 * (2k+1))
#define E1  3.2053337e-1f
#define E3  3.2931300e-2f
#define E5  3.3834000e-3f
#define E7  3.4760500e-4f
#define E9  3.5712900e-5f
#define E11 3.6691300e-6f
#define E13 3.7696000e-7f
#define E15 3.8729500e-8f

__device__ __forceinline__ void compute_features(
    int tid, int Ri, int Ci,
    const float* __restrict__ W_pos, const float* __restrict__ b_pos,
    const int* jR, const int* jC,
    const float (*natoms)[15], const float* iatoms,
    unsigned char* featF8) {
    {
        const int e = tid >> 4, p = tid & 15;
        const int drel = jR[e] - Ri;
        const int same = (jC[e] == Ci);
        int dc = drel + 32;
        dc = dc < 0 ? 0 : (dc > 64 ? 64 : dc);
        const int df = same ? dc : 65;
        const float v = W_pos[p * 66 + df] + b_pos[p];
        const int pb = __builtin_amdgcn_cvt_pk_fp8_f32(v, 0.0f, 0, false);
        featF8[e * FS + p] = (unsigned char)(pb & 0xFF);
    }
#pragma unroll
    for (int it = 0; it < 2; ++it) {
        const int task = tid + it * 512;
        if (task < 800) {
            const int mn = task >> 5, e = task & 31;
            const int m = mn / 5, n = mn - m * 5;
            const float ax = iatoms[m * 3 + 0];
            const float ay = iatoms[m * 3 + 1];
            const float az = iatoms[m * 3 + 2];
            const float* na = &natoms[e][n * 3];
            const float dx = ax - na[0], dy = ay - na[1], dz = az - na[2];
            const float D = sqrtf(dx * dx + dy * dy + dz * dz + 1e-6f);
            // RBF chain anchored at mu_8 = 12.6667: rbf[8+k] = A * C^k * exp(-1.1378 k^2)
            float v = D - 12.6666667f;
            v = fminf(fmaxf(v, -14.0f), 14.0f);
            const float A  = __expf(-0.64f * v * v);
            const float C  = __expf(1.70666667f * v);
            const float Ci_ = 1.0f / C;
            const float f8 = A;
            const float f9  = f8  * C * E1;
            const float f10 = f9  * C * E3;
            const float f11 = f10 * C * E5;
            const float f12 = f11 * C * E7;
            const float f13 = f12 * C * E9;
            const float f14 = f13 * C * E11;
            const float f15 = f14 * C * E13;
            const float f7 = f8 * Ci_ * E1;
            const float f6 = f7 * Ci_ * E3;
            const float f5 = f6 * Ci_ * E5;
            const float f4 = f5 * Ci_ * E7;
            const float f3 = f4 * Ci_ * E9;
            const float f2 = f3 * Ci_ * E11;
            const float f1 = f2 * Ci_ * E13;
            const float f0 = f1 * Ci_ * E15;
            int4 w4;
            w4.x = pk4(f0, f1, f2, f3);
            w4.y = pk4(f4, f5, f6, f7);
            w4.z = pk4(f8, f9, f10, f11);
            w4.w = pk4(f12, f13, f14, f15);
            *(int4*)(featF8 + e * FS + 16 + mn * 16) = w4;
        }
    }
}

__global__ __launch_bounds__(512, 6) void edge_kernel(
    const float* __restrict__ X,
    const int* __restrict__ Ridx, const int* __restrict__ Chain,
    const float* __restrict__ W_pos, const float* __restrict__ b_pos,
    const unsigned char* __restrict__ Wf8,
    const float* __restrict__ lng, const float* __restrict__ lnb,
    const float4* __restrict__ CAm,
    float* __restrict__ eidx_out, float* __restrict__ outE) {
    const int tid = threadIdx.x;
    const int row0 = blockIdx.x * 4;
    const int b = row0 >> 11;                 // 2048 % 4 == 0: no batch straddle
    const int i0 = row0 & (LEN - 1);

    // union pool: topk {cand[2048] u64 | hist[512] int} vs main {featF8 | hbuf}
    __shared__ __align__(16) unsigned char pool[30720];
    __shared__ float natoms[4][32][15];                     // 7680 B
    __shared__ float iatoms[4][16];                         //  256 B
    __shared__ int jR[4][KNB], jC[4][KNB], jidx[4][KNB];    // 1536 B
    __shared__ int riS[4], ciS[4];
    __shared__ int candcnt, selB;

    ull* cand = (ull*)pool;                        // 16384 B
    int* hist = (int*)(pool + 16384);              //  2048 B
    unsigned char* featF8 = pool;                  // 13824 B
    float* hbuf = (float*)(pool + 13824);          // 16896 B

    const float4* Cc = CAm + (size_t)b * LEN;

    // ---------------- Phase T: exact top-32 for the 4 rows ----------------
    for (int r = 0; r < 4; ++r) {
        hist[tid] = 0;
        if (tid == 0) candcnt = 0;
        __syncthreads();
        const float4 ci = Cc[i0 + r];
        uint32 d2b[4];
#pragma unroll
        for (int q = 0; q < 4; ++q) {
            const float4 cj = Cc[q * 512 + tid];
            float dx = __fsub_rn(ci.x, cj.x);
            float dy = __fsub_rn(ci.y, cj.y);
            float dz = __fsub_rn(ci.z, cj.z);
            float d2 = __fadd_rn(__fadd_rn(__fmul_rn(dx, dx), __fmul_rn(dy, dy)),
                                 __fmul_rn(dz, dz));
            d2 = __fadd_rn(d2, cj.w);
            d2b[q] = __float_as_uint(d2);
        }
#pragma unroll
        for (int q = 0; q < 4; ++q) atomicAdd(&hist[d2b[q] >> 22], 1);
        __syncthreads();

        if (tid < 64) {   // scan: find minimal bucket B with cum count >= 32
            int loc[8];
            int s = 0;
#pragma unroll
            for (int t = 0; t < 8; ++t) { loc[t] = hist[tid * 8 + t]; s += loc[t]; }
            int incl = s;
#pragma unroll
            for (int off = 1; off < 64; off <<= 1) {
                int o = __shfl_up(incl, off, 64);
                if (tid >= off) incl += o;
            }
            const int excl = incl - s;
            if (excl < KNB && incl >= KNB) {
                int c = excl;
#pragma unroll
                for (int t = 0; t < 8; ++t) {
                    int c2 = c + loc[t];
                    if (c < KNB && c2 >= KNB) selB = tid * 8 + t;
                    c = c2;
                }
            }
        }
        __syncthreads();
        const uint32 B = (uint32)selB;

#pragma unroll
        for (int q = 0; q < 4; ++q) {
            if ((d2b[q] >> 22) <= B) {
                int p = atomicAdd(&candcnt, 1);
                cand[p] = (((ull)d2b[q]) << 32) | (uint32)(q * 512 + tid);
            }
        }
        __syncthreads();
        const int M = candcnt;

        for (int c = tid; c < M; c += 512) {
            const ull k = cand[c];
            int rk = 0;
            for (int m = 0; m < M; ++m) rk += (cand[m] < k);
            if (rk < KNB) {
                const int j = (int)(uint32)(k & 0xFFFFFFFFull);
                eidx_out[(size_t)(row0 + r) * KNB + rk] = (float)j;
                jidx[r][rk] = j;
            }
        }
        __syncthreads();
    }

    // ---------------- W register residency (fp8, 26 regs/lane) ----------------
    const int w = tid >> 6, l = tid & 63, lr = l & 15, lg = l >> 4;
    long wreg[13];
    {
        const unsigned char* wb = Wf8 + (size_t)(w * 16 + lr) * 416 + lg * 8;
#pragma unroll
        for (int ks = 0; ks < 13; ++ks)
            wreg[ks] = *(const long*)(wb + ks * 32);
    }

    // ---------------- gather prologue: all 4 rows ----------------
    const float* Xb = X + (size_t)b * LEN * 12;
    if (tid < 128) {
        const int r = tid >> 5, e = tid & 31;
        const int j = jidx[r][e];
        jR[r][e] = Ridx[b * LEN + j];
        jC[r][e] = Chain[b * LEN + j];
        load_res_atoms(Xb + j * 12, &natoms[r][e][0]);
    } else if (tid < 132) {
        const int r = tid - 128;
        load_res_atoms(Xb + (size_t)(i0 + r) * 12, &iatoms[r][0]);
    } else if (tid < 136) {
        riS[tid - 132] = Ridx[b * LEN + i0 + (tid - 132)];
    } else if (tid < 140) {
        ciS[tid - 136] = Chain[b * LEN + i0 + (tid - 136)];
    }
    __syncthreads();

    compute_features(tid, riS[0], ciS[0], W_pos, b_pos,
                     jR[0], jC[0], natoms[0], iatoms[0], featF8);
    __syncthreads();

    for (int r = 0; r < 4; ++r) {
        const int row = row0 + r;

        // === region B: fp8 GEMM(r) + scatter acc -> hbuf ===
        f32x4 acc0 = {0.f, 0.f, 0.f, 0.f}, acc1 = acc0;
        {
            const unsigned char* fb0 = featF8 + lr * FS + lg * 8;
            const unsigned char* fb1 = featF8 + (16 + lr) * FS + lg * 8;
#pragma unroll
            for (int ks = 0; ks < 13; ++ks) {
                const long a0 = *(const long*)(fb0 + ks * 32);
                const long a1 = *(const long*)(fb1 + ks * 32);
                acc0 = __builtin_amdgcn_mfma_f32_16x16x32_fp8_fp8(a0, wreg[ks], acc0, 0, 0, 0);
                acc1 = __builtin_amdgcn_mfma_f32_16x16x32_fp8_fp8(a1, wreg[ks], acc1, 0, 0, 0);
            }
        }
#pragma unroll
        for (int rr = 0; rr < 4; ++rr) {
            hbuf[(lg * 4 + rr) * 132 + w * 16 + lr]      = acc0[rr];
            hbuf[(16 + lg * 4 + rr) * 132 + w * 16 + lr] = acc1[rr];
        }
        __syncthreads();

        // === region C: LN(r) from hbuf + store; features(r+1) ===
        {
            const int g = tid >> 4, l2 = tid & 15;
            const float4* hb4 = (const float4*)(hbuf + g * 132 + l2 * 8);
            const float4 v0 = hb4[0], v1 = hb4[1];
            float s = v0.x + v0.y + v0.z + v0.w + v1.x + v1.y + v1.z + v1.w;
            float ssq = v0.x * v0.x + v0.y * v0.y + v0.z * v0.z + v0.w * v0.w
                      + v1.x * v1.x + v1.y * v1.y + v1.z * v1.z + v1.w * v1.w;
#pragma unroll
            for (int off = 1; off < 16; off <<= 1) {
                s += __shfl_xor(s, off, 64);
                ssq += __shfl_xor(ssq, off, 64);
            }
            const float mean = s * (1.0f / 128.0f);
            const float rstd = rsqrtf(ssq * (1.0f / 128.0f) - mean * mean + 1e-5f);

            float4* ob = (float4*)(outE + ((size_t)row * KNB + g) * HID + l2 * 8);
            const float4 g0 = *(const float4*)(lng + l2 * 8);
            const float4 g1 = *(const float4*)(lng + l2 * 8 + 4);
            const float4 b0 = *(const float4*)(lnb + l2 * 8);
            const float4 b1 = *(const float4*)(lnb + l2 * 8 + 4);
            float4 o0, o1;
            o0.x = (v0.x - mean) * rstd * g0.x + b0.x;
            o0.y = (v0.y - mean) * rstd * g0.y + b0.y;
            o0.z = (v0.z - mean) * rstd * g0.z + b0.z;
            o0.w = (v0.w - mean) * rstd * g0.w + b0.w;
            o1.x = (v1.x - mean) * rstd * g1.x + b1.x;
            o1.y = (v1.y - mean) * rstd * g1.y + b1.y;
            o1.z = (v1.z - mean) * rstd * g1.z + b1.z;
            o1.w = (v1.w - mean) * rstd * g1.w + b1.w;
            ob[0] = o0;
            ob[1] = o1;
        }
        if (r < 3) {
            compute_features(tid, riS[r + 1], ciS[r + 1], W_pos, b_pos,
                             jR[r + 1], jC[r + 1], natoms[r + 1], iatoms[r + 1],
                             featF8);
        }
        __syncthreads();
    }
}

extern "C" void kernel_launch(void* const* d_in, const int* in_sizes, int n_in,
                              void* d_out, int out_size, void* d_ws, size_t ws_size,
                              hipStream_t stream) {
    const float* X      = (const float*)d_in[0];
    const float* mask   = (const float*)d_in[1];
    const int*   Ridx   = (const int*)d_in[2];
    const int*   Chain  = (const int*)d_in[3];
    const float* W_pos  = (const float*)d_in[4];
    const float* b_pos  = (const float*)d_in[5];
    const float* W_edge = (const float*)d_in[6];
    const float* lng    = (const float*)d_in[7];
    const float* lnb    = (const float*)d_in[8];

    float* out  = (float*)d_out;
    float* eidx = out;                           // B*L*K floats (exact ints)
    float* E    = out + (size_t)2 * LEN * KNB;   // B*L*K*HID floats

    float4* CAm = (float4*)d_ws;                                  // 64 KiB
    unsigned char* Wf8 = (unsigned char*)d_ws + 2 * LEN * 16;     // 52 KiB

    prep_kernel<<<52, 256, 0, stream>>>(X, mask, W_edge, CAm, (int*)Wf8);
    edge_kernel<<<(2 * LEN) / 4, 512, 0, stream>>>(X, Ridx, Chain, W_pos, b_pos,
                                                   Wf8, lng, lnb, CAm, eidx, E);
}

// Round 10
// 64.006 us; speedup vs baseline: 1.2517x; 1.2517x over previous
//
#include <hip/hip_runtime.h>
#include <hip/hip_bf16.h>

#define LEN   2048
#define KNB   32
#define HID   128
#define FS    512   // fp8 bytes/feature-row: 32 16B-blocks, XOR-swizzle closed

typedef unsigned long long ull;
typedef unsigned int uint32;
typedef float f32x4 __attribute__((ext_vector_type(4)));

// ---------------------------------------------------------------------------
// Kernel 0: prep — pack CA+mask as float4; convert W_edge f32 -> fp8 e4m3.
// ---------------------------------------------------------------------------
__global__ __launch_bounds__(256) void prep_kernel(
    const float* __restrict__ X, const float* __restrict__ mask,
    const float* __restrict__ W_edge,
    float4* __restrict__ CAm, int* __restrict__ Wf8) {
    const int t = blockIdx.x * 256 + threadIdx.x;
    if (t < 2 * LEN) {
        const float* p = X + (size_t)t * 12;
        CAm[t] = make_float4(p[3], p[4], p[5],
                             __fmul_rn(__fsub_rn(1.0f, mask[t]), 1000000.0f));
    }
    if (t < 13312) {
        const float4 w = ((const float4*)W_edge)[t];
        int r = __builtin_amdgcn_cvt_pk_fp8_f32(w.x, w.y, 0, false);
        r = __builtin_amdgcn_cvt_pk_fp8_f32(w.z, w.w, r, true);
        Wf8[t] = r;
    }
}

// ---------------------------------------------------------------------------
// Kernel 1: exact top-K=32 via histogram-select (proven ~10us standalone —
// R9 fusion into edge regressed 2x; keep separate).
// ---------------------------------------------------------------------------
__global__ __launch_bounds__(256) void topk_kernel(
    const float4* __restrict__ CAm, float* __restrict__ eidx_out) {
    const int row = blockIdx.x;
    const int b = row >> 11;
    const int i = row & (LEN - 1);
    const int tid = threadIdx.x;

    __shared__ int hist[512];
    __shared__ ull cand[LEN];
    __shared__ int candcnt;
    __shared__ int selB;

    const float4* C = CAm + (size_t)b * LEN;
    const float4 ci = C[i];

    uint32 d2b[8];
#pragma unroll
    for (int q = 0; q < 8; ++q) {
        const float4 cj = C[q * 256 + tid];
        float dx = __fsub_rn(ci.x, cj.x);
        float dy = __fsub_rn(ci.y, cj.y);
        float dz = __fsub_rn(ci.z, cj.z);
        float d2 = __fadd_rn(__fadd_rn(__fmul_rn(dx, dx), __fmul_rn(dy, dy)),
                             __fmul_rn(dz, dz));
        d2 = __fadd_rn(d2, cj.w);
        d2b[q] = __float_as_uint(d2);
    }

    hist[tid] = 0; hist[tid + 256] = 0;
    if (tid == 0) candcnt = 0;
    __syncthreads();
#pragma unroll
    for (int q = 0; q < 8; ++q) atomicAdd(&hist[d2b[q] >> 22], 1);
    __syncthreads();

    if (tid < 64) {
        int loc[8];
        int s = 0;
#pragma unroll
        for (int t = 0; t < 8; ++t) { loc[t] = hist[tid * 8 + t]; s += loc[t]; }
        int incl = s;
#pragma unroll
        for (int off = 1; off < 64; off <<= 1) {
            int o = __shfl_up(incl, off, 64);
            if (tid >= off) incl += o;
        }
        const int excl = incl - s;
        if (excl < KNB && incl >= KNB) {
            int c = excl;
#pragma unroll
            for (int t = 0; t < 8; ++t) {
                int c2 = c + loc[t];
                if (c < KNB && c2 >= KNB) selB = tid * 8 + t;
                c = c2;
            }
        }
    }
    __syncthreads();
    const uint32 B = (uint32)selB;

#pragma unroll
    for (int q = 0; q < 8; ++q) {
        if ((d2b[q] >> 22) <= B) {
            int p = atomicAdd(&candcnt, 1);
            cand[p] = (((ull)d2b[q]) << 32) | (uint32)(q * 256 + tid);
        }
    }
    __syncthreads();
    const int M = candcnt;

    for (int c = tid; c < M; c += 256) {
        const ull k = cand[c];
        int r = 0;
        for (int m = 0; m < M; ++m) r += (cand[m] < k);
        if (r < KNB)
            eidx_out[(size_t)row * KNB + r] = (float)(uint32)(k & 0xFFFFFFFFull);
    }
}

// ---------------------------------------------------------------------------
// Kernel 2: 4 rows/block, 512 thr (8 waves), 1024 blocks, ~42.3KB LDS ->
// 3 blocks/CU. W register-resident fp8 (26 regs, launch_bounds(512,6) —
// proven no-spill in R8). featF8: FS=512, 16B-block XOR swizzle (blk^=e&7)
// on write AND read -> A-reads at b64 hw floor (was 8-way, 3.1M conflicts).
// RBF: two-anchor recurrence (k=4, k=12), <=4 steps -> no underflow where
// fp8-visible. 3 exp + rcp + ~28 mul per (atom-pair, edge).
// ---------------------------------------------------------------------------
__device__ __forceinline__ void load_res_atoms(const float* __restrict__ p, float* dst) {
    const float Nx = p[0], Ny = p[1], Nz = p[2];
    const float Ax = p[3], Ay = p[4], Az = p[5];
    const float Cx = p[6], Cy = p[7], Cz = p[8];
    const float Ox = p[9], Oy = p[10], Oz = p[11];
    const float bx = Ax - Nx, by = Ay - Ny, bz = Az - Nz;
    const float cx = Cx - Ax, cy = Cy - Ay, cz = Cz - Az;
    const float axv = by * cz - bz * cy;
    const float ayv = bz * cx - bx * cz;
    const float azv = bx * cy - by * cx;
    dst[0] = Nx;  dst[1] = Ny;  dst[2] = Nz;
    dst[3] = Ax;  dst[4] = Ay;  dst[5] = Az;
    dst[6] = Cx;  dst[7] = Cy;  dst[8] = Cz;
    dst[9] = Ox;  dst[10] = Oy; dst[11] = Oz;
    dst[12] = -0.58273431f * axv + 0.56802827f * bx + -0.54067466f * cx + Ax;
    dst[13] = -0.58273431f * ayv + 0.56802827f * by + -0.54067466f * cy + Ay;
    dst[14] = -0.58273431f * azv + 0.56802827f * bz + -0.54067466f * cz + Az;
}

__device__ __forceinline__ int pk4(float a, float b, float c, float d) {
    int r = __builtin_amdgcn_cvt_pk_fp8_f32(a, b, 0, false);
    return __builtin_amdgcn_cvt_pk_fp8_f32(c, d, r, true);
}

// chain constants exp(-1.1377778 * (2j+1)), j = 0..3
#define E1  3.2053337e-1f
#define E3  3.2931300e-2f
#define E5  3.3834001e-3f
#define E7  3.4760500e-4f

__device__ __forceinline__ void compute_features(
    int tid, int Ri, int Ci,
    const float* __restrict__ W_pos, const float* __restrict__ b_pos,
    const int* jR, const int* jC,
    const float (*natoms)[15], const float* iatoms,
    unsigned char* featF8) {
    {
        const int e = tid >> 4, p = tid & 15;
        const int drel = jR[e] - Ri;
        const int same = (jC[e] == Ci);
        int dc = drel + 32;
        dc = dc < 0 ? 0 : (dc > 64 ? 64 : dc);
        const int df = same ? dc : 65;
        const float v = W_pos[p * 66 + df] + b_pos[p];
        const int pb = __builtin_amdgcn_cvt_pk_fp8_f32(v, 0.0f, 0, false);
        featF8[e * FS + ((e & 7) << 4) + p] = (unsigned char)(pb & 0xFF);  // blk0^s = s
    }
#pragma unroll
    for (int it = 0; it < 2; ++it) {
        const int task = tid + it * 512;
        if (task < 800) {
            const int mn = task >> 5, e = task & 31;
            const int m = mn / 5, n = mn - m * 5;
            const float ax = iatoms[m * 3 + 0];
            const float ay = iatoms[m * 3 + 1];
            const float az = iatoms[m * 3 + 2];
            const float* na = &natoms[e][n * 3];
            const float dx = ax - na[0], dy = ay - na[1], dz = az - na[2];
            const float D = sqrtf(dx * dx + dy * dy + dz * dz + 1e-6f);
            const float Dc = fminf(D, 40.0f);
            // two anchors: k=4 (mu=7.3333), k=12 (mu=18). <=4 chain steps.
            const float v4 = Dc - 7.3333333f;
            const float v12 = Dc - 18.0f;
            const float A4  = __expf(-0.64f * v4 * v4);
            const float A12 = __expf(-0.64f * v12 * v12);
            const float C4  = __expf(1.7066667f * v4);
            const float Ci4 = 1.0f / C4;
            const float C12  = C4 * 1.24140e-8f;    // exp(-1.70667*10.6667)
            const float Ci12 = Ci4 * 8.05543e7f;
            const float f4 = A4;
            const float f5 = f4 * C4 * E1;
            const float f6 = f5 * C4 * E3;
            const float f7 = f6 * C4 * E5;
            const float f3 = f4 * Ci4 * E1;
            const float f2 = f3 * Ci4 * E3;
            const float f1 = f2 * Ci4 * E5;
            const float f0 = f1 * Ci4 * E7;
            const float f12 = A12;
            const float f13 = f12 * C12 * E1;
            const float f14 = f13 * C12 * E3;
            const float f15 = f14 * C12 * E5;
            const float f11 = f12 * Ci12 * E1;
            const float f10 = f11 * Ci12 * E3;
            const float f9  = f10 * Ci12 * E5;
            const float f8  = f9  * Ci12 * E7;
            int4 w4;
            w4.x = pk4(f0, f1, f2, f3);
            w4.y = pk4(f4, f5, f6, f7);
            w4.z = pk4(f8, f9, f10, f11);
            w4.w = pk4(f12, f13, f14, f15);
            *(int4*)(featF8 + e * FS + (((1 + mn) ^ (e & 7)) << 4)) = w4;
        }
    }
}

__global__ __launch_bounds__(512, 6) void edge_kernel(
    const float* __restrict__ X,
    const int* __restrict__ Ridx, const int* __restrict__ Chain,
    const float* __restrict__ W_pos, const float* __restrict__ b_pos,
    const unsigned char* __restrict__ Wf8,
    const float* __restrict__ lng, const float* __restrict__ lnb,
    const float* __restrict__ eidx_f, float* __restrict__ outE) {
    const int tid = threadIdx.x;
    const int row0 = blockIdx.x * 4;
    const int b = row0 >> 11;                 // 2048 % 4 == 0: no batch straddle
    const int i0 = row0 & (LEN - 1);

    __shared__ __align__(16) unsigned char featF8[32 * FS];   // 16384 B
    __shared__ __align__(16) float hbuf[32 * 132];            // 16896 B
    __shared__ float natoms[4][32][15];                       //  7680 B
    __shared__ float iatoms[4][16];                           //   256 B
    __shared__ int jR[4][KNB], jC[4][KNB];                    //  1024 B
    __shared__ int riS[4], ciS[4];

    const float* Xb = X + (size_t)b * LEN * 12;

    // --- W register residency (fp8, 26 regs/lane)
    const int w = tid >> 6, l = tid & 63, lr = l & 15, lg = l >> 4;
    long wreg[13];
    {
        const unsigned char* wb = Wf8 + (size_t)(w * 16 + lr) * 416 + lg * 8;
#pragma unroll
        for (int ks = 0; ks < 13; ++ks)
            wreg[ks] = *(const long*)(wb + ks * 32);
    }

    // --- prologue: ALL 4 rows' gathers in parallel
    if (tid < 128) {
        const int r = tid >> 5, e = tid & 31;
        const int j = (int)eidx_f[(size_t)(row0 + r) * KNB + e];
        jR[r][e] = Ridx[b * LEN + j];
        jC[r][e] = Chain[b * LEN + j];
        load_res_atoms(Xb + j * 12, &natoms[r][e][0]);
    } else if (tid < 132) {
        const int r = tid - 128;
        load_res_atoms(Xb + (size_t)(i0 + r) * 12, &iatoms[r][0]);
    } else if (tid < 136) {
        riS[tid - 132] = Ridx[b * LEN + i0 + (tid - 132)];
    } else if (tid < 140) {
        ciS[tid - 136] = Chain[b * LEN + i0 + (tid - 136)];
    }
    __syncthreads();

    compute_features(tid, riS[0], ciS[0], W_pos, b_pos,
                     jR[0], jC[0], natoms[0], iatoms[0], featF8);
    __syncthreads();

    for (int r = 0; r < 4; ++r) {
        const int row = row0 + r;

        // === region B: fp8 GEMM(r) (swizzled A-reads) + scatter -> hbuf ===
        f32x4 acc0 = {0.f, 0.f, 0.f, 0.f}, acc1 = acc0;
        {
            const int sw = lr & 7;                 // (16+lr)&7 == lr&7
            const int mb = lg >> 1;
            const unsigned char* fb0 = featF8 + lr * FS + (lg & 1) * 8;
            const unsigned char* fb1 = featF8 + (16 + lr) * FS + (lg & 1) * 8;
#pragma unroll
            for (int ks = 0; ks < 13; ++ks) {
                const int moff = ((2 * ks + mb) ^ sw) << 4;
                const long a0 = *(const long*)(fb0 + moff);
                const long a1 = *(const long*)(fb1 + moff);
                acc0 = __builtin_amdgcn_mfma_f32_16x16x32_fp8_fp8(a0, wreg[ks], acc0, 0, 0, 0);
                acc1 = __builtin_amdgcn_mfma_f32_16x16x32_fp8_fp8(a1, wreg[ks], acc1, 0, 0, 0);
            }
        }
#pragma unroll
        for (int rr = 0; rr < 4; ++rr) {
            hbuf[(lg * 4 + rr) * 132 + w * 16 + lr]      = acc0[rr];
            hbuf[(16 + lg * 4 + rr) * 132 + w * 16 + lr] = acc1[rr];
        }
        __syncthreads();

        // === region C: LN(r) from hbuf + store; features(r+1) ===
        {
            const int g = tid >> 4, l2 = tid & 15;
            const float4* hb4 = (const float4*)(hbuf + g * 132 + l2 * 8);
            const float4 v0 = hb4[0], v1 = hb4[1];
            float s = v0.x + v0.y + v0.z + v0.w + v1.x + v1.y + v1.z + v1.w;
            float ssq = v0.x * v0.x + v0.y * v0.y + v0.z * v0.z + v0.w * v0.w
                      + v1.x * v1.x + v1.y * v1.y + v1.z * v1.z + v1.w * v1.w;
#pragma unroll
            for (int off = 1; off < 16; off <<= 1) {
                s += __shfl_xor(s, off, 64);
                ssq += __shfl_xor(ssq, off, 64);
            }
            const float mean = s * (1.0f / 128.0f);
            const float rstd = rsqrtf(ssq * (1.0f / 128.0f) - mean * mean + 1e-5f);

            float4* ob = (float4*)(outE + ((size_t)row * KNB + g) * HID + l2 * 8);
            const float4 g0 = *(const float4*)(lng + l2 * 8);
            const float4 g1 = *(const float4*)(lng + l2 * 8 + 4);
            const float4 b0 = *(const float4*)(lnb + l2 * 8);
            const float4 b1 = *(const float4*)(lnb + l2 * 8 + 4);
            float4 o0, o1;
            o0.x = (v0.x - mean) * rstd * g0.x + b0.x;
            o0.y = (v0.y - mean) * rstd * g0.y + b0.y;
            o0.z = (v0.z - mean) * rstd * g0.z + b0.z;
            o0.w = (v0.w - mean) * rstd * g0.w + b0.w;
            o1.x = (v1.x - mean) * rstd * g1.x + b1.x;
            o1.y = (v1.y - mean) * rstd * g1.y + b1.y;
            o1.z = (v1.z - mean) * rstd * g1.z + b1.z;
            o1.w = (v1.w - mean) * rstd * g1.w + b1.w;
            ob[0] = o0;
            ob[1] = o1;
        }
        if (r < 3) {
            compute_features(tid, riS[r + 1], ciS[r + 1], W_pos, b_pos,
                             jR[r + 1], jC[r + 1], natoms[r + 1], iatoms[r + 1],
                             featF8);
        }
        __syncthreads();
    }
}

extern "C" void kernel_launch(void* const* d_in, const int* in_sizes, int n_in,
                              void* d_out, int out_size, void* d_ws, size_t ws_size,
                              hipStream_t stream) {
    const float* X      = (const float*)d_in[0];
    const float* mask   = (const float*)d_in[1];
    const int*   Ridx   = (const int*)d_in[2];
    const int*   Chain  = (const int*)d_in[3];
    const float* W_pos  = (const float*)d_in[4];
    const float* b_pos  = (const float*)d_in[5];
    const float* W_edge = (const float*)d_in[6];
    const float* lng    = (const float*)d_in[7];
    const float* lnb    = (const float*)d_in[8];

    float* out  = (float*)d_out;
    float* eidx = out;                           // B*L*K floats (exact ints)
    float* E    = out + (size_t)2 * LEN * KNB;   // B*L*K*HID floats

    float4* CAm = (float4*)d_ws;                                  // 64 KiB
    unsigned char* Wf8 = (unsigned char*)d_ws + 2 * LEN * 16;     // 52 KiB

    const int nrow = 2 * LEN;
    prep_kernel<<<52, 256, 0, stream>>>(X, mask, W_edge, CAm, (int*)Wf8);
    topk_kernel<<<nrow, 256, 0, stream>>>(CAm, eidx);
    edge_kernel<<<nrow / 4, 512, 0, stream>>>(X, Ridx, Chain, W_pos, b_pos, Wf8,
                                              lng, lnb, eidx, E);
}

// Round 11
// 62.061 us; speedup vs baseline: 1.2909x; 1.0313x over previous
//
#include <hip/hip_runtime.h>
#include <hip/hip_bf16.h>

#define LEN   2048
#define KNB   32
#define HID   128
#define FS    512   // fp8 bytes/feature-row: 32 16B-blocks, XOR-swizzle closed

typedef unsigned long long ull;
typedef unsigned int uint32;
typedef float f32x4 __attribute__((ext_vector_type(4)));

// LDS-only barrier: output stores (vmcnt) stay in flight across rows.
// Safe here: nothing in-block ever reads the global stores back.
__device__ __forceinline__ void bar_lgkm() {
    asm volatile("s_waitcnt lgkmcnt(0)" ::: "memory");
    __builtin_amdgcn_s_barrier();
    asm volatile("" ::: "memory");
}

// ---------------------------------------------------------------------------
// Kernel 0: prep — pack CA+mask as float4; convert W_edge f32 -> fp8 e4m3.
// ---------------------------------------------------------------------------
__global__ __launch_bounds__(256) void prep_kernel(
    const float* __restrict__ X, const float* __restrict__ mask,
    const float* __restrict__ W_edge,
    float4* __restrict__ CAm, int* __restrict__ Wf8) {
    const int t = blockIdx.x * 256 + threadIdx.x;
    if (t < 2 * LEN) {
        const float* p = X + (size_t)t * 12;
        CAm[t] = make_float4(p[3], p[4], p[5],
                             __fmul_rn(__fsub_rn(1.0f, mask[t]), 1000000.0f));
    }
    if (t < 13312) {
        const float4 w = ((const float4*)W_edge)[t];
        int r = __builtin_amdgcn_cvt_pk_fp8_f32(w.x, w.y, 0, false);
        r = __builtin_amdgcn_cvt_pk_fp8_f32(w.z, w.w, r, true);
        Wf8[t] = r;
    }
}

// ---------------------------------------------------------------------------
// Kernel 1: exact top-K=32 via histogram-select (proven ~10us standalone).
// ---------------------------------------------------------------------------
__global__ __launch_bounds__(256) void topk_kernel(
    const float4* __restrict__ CAm, float* __restrict__ eidx_out) {
    const int row = blockIdx.x;
    const int b = row >> 11;
    const int i = row & (LEN - 1);
    const int tid = threadIdx.x;

    __shared__ int hist[512];
    __shared__ ull cand[LEN];
    __shared__ int candcnt;
    __shared__ int selB;

    const float4* C = CAm + (size_t)b * LEN;
    const float4 ci = C[i];

    uint32 d2b[8];
#pragma unroll
    for (int q = 0; q < 8; ++q) {
        const float4 cj = C[q * 256 + tid];
        float dx = __fsub_rn(ci.x, cj.x);
        float dy = __fsub_rn(ci.y, cj.y);
        float dz = __fsub_rn(ci.z, cj.z);
        float d2 = __fadd_rn(__fadd_rn(__fmul_rn(dx, dx), __fmul_rn(dy, dy)),
                             __fmul_rn(dz, dz));
        d2 = __fadd_rn(d2, cj.w);
        d2b[q] = __float_as_uint(d2);
    }

    hist[tid] = 0; hist[tid + 256] = 0;
    if (tid == 0) candcnt = 0;
    __syncthreads();
#pragma unroll
    for (int q = 0; q < 8; ++q) atomicAdd(&hist[d2b[q] >> 22], 1);
    __syncthreads();

    if (tid < 64) {
        int loc[8];
        int s = 0;
#pragma unroll
        for (int t = 0; t < 8; ++t) { loc[t] = hist[tid * 8 + t]; s += loc[t]; }
        int incl = s;
#pragma unroll
        for (int off = 1; off < 64; off <<= 1) {
            int o = __shfl_up(incl, off, 64);
            if (tid >= off) incl += o;
        }
        const int excl = incl - s;
        if (excl < KNB && incl >= KNB) {
            int c = excl;
#pragma unroll
            for (int t = 0; t < 8; ++t) {
                int c2 = c + loc[t];
                if (c < KNB && c2 >= KNB) selB = tid * 8 + t;
                c = c2;
            }
        }
    }
    __syncthreads();
    const uint32 B = (uint32)selB;

#pragma unroll
    for (int q = 0; q < 8; ++q) {
        if ((d2b[q] >> 22) <= B) {
            int p = atomicAdd(&candcnt, 1);
            cand[p] = (((ull)d2b[q]) << 32) | (uint32)(q * 256 + tid);
        }
    }
    __syncthreads();
    const int M = candcnt;

    for (int c = tid; c < M; c += 256) {
        const ull k = cand[c];
        int r = 0;
        for (int m = 0; m < M; ++m) r += (cand[m] < k);
        if (r < KNB)
            eidx_out[(size_t)row * KNB + r] = (float)(uint32)(k & 0xFFFFFFFFull);
    }
}

// ---------------------------------------------------------------------------
// Kernel 2: 4 rows/block, 512 thr, 1024 blocks. W register-resident fp8.
// lgkm-only barriers (stores fly across rows). W_pos+b_pos pre-summed in LDS.
// RBF two-anchor recurrence with segment-local packing (low reg pressure).
// ---------------------------------------------------------------------------
__device__ __forceinline__ void load_res_atoms(const float* __restrict__ p, float* dst) {
    const float Nx = p[0], Ny = p[1], Nz = p[2];
    const float Ax = p[3], Ay = p[4], Az = p[5];
    const float Cx = p[6], Cy = p[7], Cz = p[8];
    const float Ox = p[9], Oy = p[10], Oz = p[11];
    const float bx = Ax - Nx, by = Ay - Ny, bz = Az - Nz;
    const float cx = Cx - Ax, cy = Cy - Ay, cz = Cz - Az;
    const float axv = by * cz - bz * cy;
    const float ayv = bz * cx - bx * cz;
    const float azv = bx * cy - by * cx;
    dst[0] = Nx;  dst[1] = Ny;  dst[2] = Nz;
    dst[3] = Ax;  dst[4] = Ay;  dst[5] = Az;
    dst[6] = Cx;  dst[7] = Cy;  dst[8] = Cz;
    dst[9] = Ox;  dst[10] = Oy; dst[11] = Oz;
    dst[12] = -0.58273431f * axv + 0.56802827f * bx + -0.54067466f * cx + Ax;
    dst[13] = -0.58273431f * ayv + 0.56802827f * by + -0.54067466f * cy + Ay;
    dst[14] = -0.58273431f * azv + 0.56802827f * bz + -0.54067466f * cz + Az;
}

__device__ __forceinline__ int pk4(float a, float b, float c, float d) {
    int r = __builtin_amdgcn_cvt_pk_fp8_f32(a, b, 0, false);
    return __builtin_amdgcn_cvt_pk_fp8_f32(c, d, r, true);
}

// chain constants exp(-1.1377778 * (2j+1)), j = 0..3
#define E1  3.2053337e-1f
#define E3  3.2931300e-2f
#define E5  3.3834001e-3f
#define E7  3.4760500e-4f

__device__ __forceinline__ void compute_features(
    int tid, int Ri, int Ci,
    const float* __restrict__ wposL,
    const int* jR, const int* jC,
    const float (*natoms)[15], const float* iatoms,
    unsigned char* featF8) {
    {
        const int e = tid >> 4, p = tid & 15;
        const int drel = jR[e] - Ri;
        const int same = (jC[e] == Ci);
        int dc = drel + 32;
        dc = dc < 0 ? 0 : (dc > 64 ? 64 : dc);
        const int df = same ? dc : 65;
        const float v = wposL[p * 66 + df];
        const int pb = __builtin_amdgcn_cvt_pk_fp8_f32(v, 0.0f, 0, false);
        featF8[e * FS + ((e & 7) << 4) + p] = (unsigned char)(pb & 0xFF);
    }
#pragma unroll
    for (int it = 0; it < 2; ++it) {
        const int task = tid + it * 512;
        if (task < 800) {
            const int mn = task >> 5, e = task & 31;
            const int m = mn / 5, n = mn - m * 5;
            const float ax = iatoms[m * 3 + 0];
            const float ay = iatoms[m * 3 + 1];
            const float az = iatoms[m * 3 + 2];
            const float* na = &natoms[e][n * 3];
            const float dx = ax - na[0], dy = ay - na[1], dz = az - na[2];
            const float D = sqrtf(dx * dx + dy * dy + dz * dz + 1e-6f);
            const float Dc = fminf(D, 40.0f);
            // two anchors (k=4: mu=7.3333, k=12: mu=18), <=4 chain steps each;
            // each segment packed immediately to cap live registers (R10 spilled).
            const float v4 = Dc - 7.3333333f;
            const float A4  = __expf(-0.64f * v4 * v4);
            const float C4  = __expf(1.7066667f * v4);
            const float Ci4 = 1.0f / C4;
            int4 w4;
            {
                const float f3 = A4 * Ci4 * E1;
                const float f2 = f3 * Ci4 * E3;
                const float f1 = f2 * Ci4 * E5;
                const float f0 = f1 * Ci4 * E7;
                w4.x = pk4(f0, f1, f2, f3);
            }
            {
                const float f5 = A4 * C4 * E1;
                const float f6 = f5 * C4 * E3;
                const float f7 = f6 * C4 * E5;
                w4.y = pk4(A4, f5, f6, f7);
            }
            const float v12 = Dc - 18.0f;
            const float A12  = __expf(-0.64f * v12 * v12);
            const float C12  = C4 * 1.24140e-8f;    // exp(-1.70667*10.6667)
            const float Ci12 = Ci4 * 8.05543e7f;
            {
                const float f11 = A12 * Ci12 * E1;
                const float f10 = f11 * Ci12 * E3;
                const float f9  = f10 * Ci12 * E5;
                const float f8  = f9  * Ci12 * E7;
                w4.z = pk4(f8, f9, f10, f11);
            }
            {
                const float f13 = A12 * C12 * E1;
                const float f14 = f13 * C12 * E3;
                const float f15 = f14 * C12 * E5;
                w4.w = pk4(A12, f13, f14, f15);
            }
            *(int4*)(featF8 + e * FS + (((1 + mn) ^ (e & 7)) << 4)) = w4;
        }
    }
}

__global__ __launch_bounds__(512, 6) void edge_kernel(
    const float* __restrict__ X,
    const int* __restrict__ Ridx, const int* __restrict__ Chain,
    const float* __restrict__ W_pos, const float* __restrict__ b_pos,
    const unsigned char* __restrict__ Wf8,
    const float* __restrict__ lng, const float* __restrict__ lnb,
    const float* __restrict__ eidx_f, float* __restrict__ outE) {
    const int tid = threadIdx.x;
    const int row0 = blockIdx.x * 4;
    const int b = row0 >> 11;                 // 2048 % 4 == 0: no batch straddle
    const int i0 = row0 & (LEN - 1);

    __shared__ __align__(16) unsigned char featF8[32 * FS];   // 16384 B
    __shared__ __align__(16) float hbuf[32 * 132];            // 16896 B
    __shared__ float natoms[4][32][15];                       //  7680 B
    __shared__ float iatoms[4][16];                           //   256 B
    __shared__ float wposL[16 * 66];                          //  4224 B
    __shared__ int jR[4][KNB], jC[4][KNB];                    //  1024 B
    __shared__ int riS[4], ciS[4];

    const float* Xb = X + (size_t)b * LEN * 12;

    // --- W register residency (fp8, 26 regs/lane)
    const int w = tid >> 6, l = tid & 63, lr = l & 15, lg = l >> 4;
    long wreg[13];
    {
        const unsigned char* wb = Wf8 + (size_t)(w * 16 + lr) * 416 + lg * 8;
#pragma unroll
        for (int ks = 0; ks < 13; ++ks)
            wreg[ks] = *(const long*)(wb + ks * 32);
    }

    // --- prologue: W_pos+b_pos pre-summed to LDS; all 4 rows' gathers
    for (int t = tid; t < 1056; t += 512)
        wposL[t] = W_pos[t] + b_pos[t / 66];
    if (tid < 128) {
        const int r = tid >> 5, e = tid & 31;
        const int j = (int)eidx_f[(size_t)(row0 + r) * KNB + e];
        jR[r][e] = Ridx[b * LEN + j];
        jC[r][e] = Chain[b * LEN + j];
        load_res_atoms(Xb + j * 12, &natoms[r][e][0]);
    } else if (tid < 132) {
        const int r = tid - 128;
        load_res_atoms(Xb + (size_t)(i0 + r) * 12, &iatoms[r][0]);
    } else if (tid < 136) {
        riS[tid - 132] = Ridx[b * LEN + i0 + (tid - 132)];
    } else if (tid < 140) {
        ciS[tid - 136] = Chain[b * LEN + i0 + (tid - 136)];
    }
    bar_lgkm();

    compute_features(tid, riS[0], ciS[0], wposL,
                     jR[0], jC[0], natoms[0], iatoms[0], featF8);
    bar_lgkm();

    for (int r = 0; r < 4; ++r) {
        const int row = row0 + r;

        // === region B: fp8 GEMM(r) (swizzled A-reads) + scatter -> hbuf ===
        f32x4 acc0 = {0.f, 0.f, 0.f, 0.f}, acc1 = acc0;
        {
            const int sw = lr & 7;                 // (16+lr)&7 == lr&7
            const int mb = lg >> 1;
            const unsigned char* fb0 = featF8 + lr * FS + (lg & 1) * 8;
            const unsigned char* fb1 = featF8 + (16 + lr) * FS + (lg & 1) * 8;
#pragma unroll
            for (int ks = 0; ks < 13; ++ks) {
                const int moff = ((2 * ks + mb) ^ sw) << 4;
                const long a0 = *(const long*)(fb0 + moff);
                const long a1 = *(const long*)(fb1 + moff);
                acc0 = __builtin_amdgcn_mfma_f32_16x16x32_fp8_fp8(a0, wreg[ks], acc0, 0, 0, 0);
                acc1 = __builtin_amdgcn_mfma_f32_16x16x32_fp8_fp8(a1, wreg[ks], acc1, 0, 0, 0);
            }
        }
#pragma unroll
        for (int rr = 0; rr < 4; ++rr) {
            hbuf[(lg * 4 + rr) * 132 + w * 16 + lr]      = acc0[rr];
            hbuf[(16 + lg * 4 + rr) * 132 + w * 16 + lr] = acc1[rr];
        }
        bar_lgkm();

        // === region C: LN(r) from hbuf + store; features(r+1) ===
        {
            const int g = tid >> 4, l2 = tid & 15;
            const float4* hb4 = (const float4*)(hbuf + g * 132 + l2 * 8);
            const float4 v0 = hb4[0], v1 = hb4[1];
            float s = v0.x + v0.y + v0.z + v0.w + v1.x + v1.y + v1.z + v1.w;
            float ssq = v0.x * v0.x + v0.y * v0.y + v0.z * v0.z + v0.w * v0.w
                      + v1.x * v1.x + v1.y * v1.y + v1.z * v1.z + v1.w * v1.w;
#pragma unroll
            for (int off = 1; off < 16; off <<= 1) {
                s += __shfl_xor(s, off, 64);
                ssq += __shfl_xor(ssq, off, 64);
            }
            const float mean = s * (1.0f / 128.0f);
            const float rstd = rsqrtf(ssq * (1.0f / 128.0f) - mean * mean + 1e-5f);

            float4* ob = (float4*)(outE + ((size_t)row * KNB + g) * HID + l2 * 8);
            const float4 g0 = *(const float4*)(lng + l2 * 8);
            const float4 g1 = *(const float4*)(lng + l2 * 8 + 4);
            const float4 b0 = *(const float4*)(lnb + l2 * 8);
            const float4 b1 = *(const float4*)(lnb + l2 * 8 + 4);
            float4 o0, o1;
            o0.x = (v0.x - mean) * rstd * g0.x + b0.x;
            o0.y = (v0.y - mean) * rstd * g0.y + b0.y;
            o0.z = (v0.z - mean) * rstd * g0.z + b0.z;
            o0.w = (v0.w - mean) * rstd * g0.w + b0.w;
            o1.x = (v1.x - mean) * rstd * g1.x + b1.x;
            o1.y = (v1.y - mean) * rstd * g1.y + b1.y;
            o1.z = (v1.z - mean) * rstd * g1.z + b1.z;
            o1.w = (v1.w - mean) * rstd * g1.w + b1.w;
            ob[0] = o0;
            ob[1] = o1;
        }
        if (r < 3) {
            compute_features(tid, riS[r + 1], ciS[r + 1], wposL,
                             jR[r + 1], jC[r + 1], natoms[r + 1], iatoms[r + 1],
                             featF8);
        }
        bar_lgkm();
    }
}

extern "C" void kernel_launch(void* const* d_in, const int* in_sizes, int n_in,
                              void* d_out, int out_size, void* d_ws, size_t ws_size,
                              hipStream_t stream) {
    const float* X      = (const float*)d_in[0];
    const float* mask   = (const float*)d_in[1];
    const int*   Ridx   = (const int*)d_in[2];
    const int*   Chain  = (const int*)d_in[3];
    const float* W_pos  = (const float*)d_in[4];
    const float* b_pos  = (const float*)d_in[5];
    const float* W_edge = (const float*)d_in[6];
    const float* lng    = (const float*)d_in[7];
    const float* lnb    = (const float*)d_in[8];

    float* out  = (float*)d_out;
    float* eidx = out;                           // B*L*K floats (exact ints)
    float* E    = out + (size_t)2 * LEN * KNB;   // B*L*K*HID floats

    float4* CAm = (float4*)d_ws;                                  // 64 KiB
    unsigned char* Wf8 = (unsigned char*)d_ws + 2 * LEN * 16;     // 52 KiB

    const int nrow = 2 * LEN;
    prep_kernel<<<52, 256, 0, stream>>>(X, mask, W_edge, CAm, (int*)Wf8);
    topk_kernel<<<nrow, 256, 0, stream>>>(CAm, eidx);
    edge_kernel<<<nrow / 4, 512, 0, stream>>>(X, Ridx, Chain, W_pos, b_pos, Wf8,
                                              lng, lnb, eidx, E);
}